// Round 1
// baseline (498.221 us; speedup 1.0000x reference)
//
#include <hip/hip_runtime.h>
#include <hip/hip_bf16.h>

// SpatialStyleModLayer fused kernel (MI355X / gfx950)
//   mod  = style @ affine_w^T + affine_b + 1            (per-row, K=256)
//   out0 = (x * mod) @ W                                (K=256)
//   ssq  = (mod*mod) @ (W*W)                            (K=256)
//   out  = out0 * rsqrt(ssq + eps) + bias
// All three GEMMs in bf16 MFMA (16x16x32), fp32 accumulate, fully fused:
// x/style read once from HBM, out written once; mod never touches HBM.

#define CH   256
#define BM   64
#define EPS  1e-8f

typedef __attribute__((ext_vector_type(4))) float f32x4;
typedef __attribute__((ext_vector_type(8))) short bf16x8;
typedef __attribute__((ext_vector_type(4))) short s16x4;

__device__ __forceinline__ short f2b(float f) {          // f32 -> bf16 (RNE)
    union { float f; unsigned u; } v; v.f = f;
    unsigned r = v.u + 0x7fffu + ((v.u >> 16) & 1u);
    return (short)(r >> 16);
}
__device__ __forceinline__ float b2f(short b) {          // bf16 -> f32
    union { unsigned u; float f; } v;
    v.u = ((unsigned)(unsigned short)b) << 16;
    return v.f;
}

// LDS pitches in shorts: +8 pad keeps 16B alignment for ds_read_b128 and
// gives bank step 4 across rows (~2-way conflict == free, m136).
#define P_S 40    // style/affine staging chunks (32 used)
#define P_M 264   // mod tile (256 used)

__global__ __launch_bounds__(256, 2)
void smod_kernel(const float* __restrict__ x, const float* __restrict__ style,
                 const float* __restrict__ weight, const float* __restrict__ bias,
                 const float* __restrict__ affw, const float* __restrict__ affb,
                 float* __restrict__ out)
{
    __shared__ __align__(16) short smem[29696];          // 59392 B
    short* style_s = smem;                               // [64][40]   phase 1
    short* aff_s   = smem + 2560;                        // [256][40]  phase 1
    short* wT_s    = smem;                               // [256][40]  phase 2 (aliases)
    short* mod_s   = smem + 12800;                       // [64][264]  persistent

    const int tid  = threadIdx.x;
    const int lane = tid & 63;
    const int wid  = tid >> 6;          // 4 waves
    const int l15  = lane & 15;
    const int lgrp = lane >> 4;         // 0..3
    const long r0  = (long)blockIdx.x * BM;

    // ---------------- Phase 1: mod^T = affine_w * style^T ----------------
    // Swapped operands so C-frag's 4 consecutive m == 4 consecutive i
    // -> vector ds_write_b64 of mod in the [row][i] layout phase 2 reads.
    f32x4 accm[4][4];
    #pragma unroll
    for (int a = 0; a < 4; ++a)
        #pragma unroll
        for (int b = 0; b < 4; ++b) { accm[a][b][0]=0.f; accm[a][b][1]=0.f; accm[a][b][2]=0.f; accm[a][b][3]=0.f; }

    for (int sc = 0; sc < 8; ++sc) {                     // s-chunks of 32
        // stage style chunk [64 rows][32 s]
        #pragma unroll
        for (int k = 0; k < 2; ++k) {
            int f = tid + (k << 8);                      // 0..511 float4s
            int r = f >> 3, s4 = (f & 7) << 2;
            f32x4 v = *(const f32x4*)(style + (r0 + r) * CH + sc * 32 + s4);
            s16x4 o = { f2b(v[0]), f2b(v[1]), f2b(v[2]), f2b(v[3]) };
            *(s16x4*)(style_s + r * P_S + s4) = o;
        }
        // stage affine chunk [256 i][32 s]  (direct copy: affw is [i][s])
        #pragma unroll
        for (int k = 0; k < 8; ++k) {
            int f = tid + (k << 8);                      // 0..2047 float4s
            int i = f >> 3, s4 = (f & 7) << 2;
            f32x4 v = *(const f32x4*)(affw + i * CH + sc * 32 + s4);
            s16x4 o = { f2b(v[0]), f2b(v[1]), f2b(v[2]), f2b(v[3]) };
            *(s16x4*)(aff_s + i * P_S + s4) = o;
        }
        __syncthreads();
        {
            const int koff = lgrp << 3;                  // one K=32 step
            bf16x8 a[4], b[4];
            #pragma unroll
            for (int it = 0; it < 4; ++it)
                a[it] = *(const bf16x8*)(aff_s + (wid * 64 + it * 16 + l15) * P_S + koff);
            #pragma unroll
            for (int rt = 0; rt < 4; ++rt)
                b[rt] = *(const bf16x8*)(style_s + (rt * 16 + l15) * P_S + koff);
            #pragma unroll
            for (int it = 0; it < 4; ++it)
                #pragma unroll
                for (int rt = 0; rt < 4; ++rt)
                    accm[it][rt] = __builtin_amdgcn_mfma_f32_16x16x32_bf16(
                        a[it], b[rt], accm[it][rt], 0, 0, 0);
        }
        __syncthreads();
    }
    // mod = acc + affine_b + 1  ->  mod_s[row][i] as bf16 (vector b64 writes)
    #pragma unroll
    for (int it = 0; it < 4; ++it) {
        int ibase = wid * 64 + it * 16 + (lgrp << 2);
        f32x4 ab = *(const f32x4*)(affb + ibase);
        #pragma unroll
        for (int rt = 0; rt < 4; ++rt) {
            int row = rt * 16 + l15;
            f32x4 m = accm[it][rt];
            s16x4 o = { f2b(m[0] + ab[0] + 1.0f), f2b(m[1] + ab[1] + 1.0f),
                        f2b(m[2] + ab[2] + 1.0f), f2b(m[3] + ab[3] + 1.0f) };
            *(s16x4*)(mod_s + row * P_M + ibase) = o;
        }
    }
    __syncthreads();

    // ---------------- Phase 2: out0 and ssq GEMMs ----------------
    f32x4 acc0[4][4], acc1[4][4];                        // [rowtile][coltile]
    #pragma unroll
    for (int a = 0; a < 4; ++a)
        #pragma unroll
        for (int b = 0; b < 4; ++b) {
            acc0[a][b][0]=0.f; acc0[a][b][1]=0.f; acc0[a][b][2]=0.f; acc0[a][b][3]=0.f;
            acc1[a][b][0]=0.f; acc1[a][b][1]=0.f; acc1[a][b][2]=0.f; acc1[a][b][3]=0.f;
        }

    for (int kc = 0; kc < 8; ++kc) {                     // i-chunks of 32
        // stage W^T chunk [256 o][32 i] via 4x4 register transpose
        #pragma unroll
        for (int k = 0; k < 2; ++k) {
            int blk = tid + (k << 8);                    // 512 blocks of 4x4
            int ib = blk & 7, ob = blk >> 3;
            int i0 = kc * 32 + ib * 4, o0 = ob * 4;
            f32x4 v0 = *(const f32x4*)(weight + (i0 + 0) * CH + o0);
            f32x4 v1 = *(const f32x4*)(weight + (i0 + 1) * CH + o0);
            f32x4 v2 = *(const f32x4*)(weight + (i0 + 2) * CH + o0);
            f32x4 v3 = *(const f32x4*)(weight + (i0 + 3) * CH + o0);
            #pragma unroll
            for (int j = 0; j < 4; ++j) {
                s16x4 wv = { f2b(v0[j]), f2b(v1[j]), f2b(v2[j]), f2b(v3[j]) };
                *(s16x4*)(wT_s + (o0 + j) * P_S + ib * 4) = wv;
            }
        }
        __syncthreads();

        const int koff = lgrp << 3;
        bf16x8 a1f[4], a2f[4];                           // x*mod and mod^2 frags
        #pragma unroll
        for (int rt = 0; rt < 4; ++rt) {
            int row = rt * 16 + l15;
            bf16x8 mb = *(const bf16x8*)(mod_s + row * P_M + kc * 32 + koff);
            const float* xp = x + (r0 + row) * CH + kc * 32 + koff;
            f32x4 x0 = *(const f32x4*)xp;
            f32x4 x1 = *(const f32x4*)(xp + 4);
            #pragma unroll
            for (int j = 0; j < 8; ++j) {
                float mf = b2f(mb[j]);
                float xj = (j < 4) ? x0[j] : x1[j - 4];
                a1f[rt][j] = f2b(mf * xj);
                a2f[rt][j] = f2b(mf * mf);
            }
        }
        #pragma unroll
        for (int ct = 0; ct < 4; ++ct) {
            int o = wid * 64 + ct * 16 + l15;
            bf16x8 bw = *(const bf16x8*)(wT_s + o * P_S + koff);
            bf16x8 bw2;
            #pragma unroll
            for (int j = 0; j < 8; ++j) {                // W^2 frag in regs
                float wf = b2f(bw[j]);
                bw2[j] = f2b(wf * wf);
            }
            #pragma unroll
            for (int rt = 0; rt < 4; ++rt) {
                acc0[rt][ct] = __builtin_amdgcn_mfma_f32_16x16x32_bf16(
                    a1f[rt], bw, acc0[rt][ct], 0, 0, 0);
                acc1[rt][ct] = __builtin_amdgcn_mfma_f32_16x16x32_bf16(
                    a2f[rt], bw2, acc1[rt][ct], 0, 0, 0);
            }
        }
        __syncthreads();
    }

    // ---------------- Epilogue: demodulate + bias, fp32 stores ----------------
    #pragma unroll
    for (int ct = 0; ct < 4; ++ct) {
        int o = wid * 64 + ct * 16 + l15;
        float bs = bias[o];
        #pragma unroll
        for (int rt = 0; rt < 4; ++rt) {
            int rowb = rt * 16 + (lgrp << 2);
            #pragma unroll
            for (int r = 0; r < 4; ++r) {
                float v = acc0[rt][ct][r] * rsqrtf(acc1[rt][ct][r] + EPS) + bs;
                out[(r0 + rowb + r) * CH + o] = v;
            }
        }
    }
}

extern "C" void kernel_launch(void* const* d_in, const int* in_sizes, int n_in,
                              void* d_out, int out_size, void* d_ws, size_t ws_size,
                              hipStream_t stream) {
    const float* x      = (const float*)d_in[0];
    const float* style  = (const float*)d_in[1];
    const float* weight = (const float*)d_in[2];
    const float* bias   = (const float*)d_in[3];
    const float* affw   = (const float*)d_in[4];
    const float* affb   = (const float*)d_in[5];
    float* outp = (float*)d_out;

    const int rows = 4 * 65536;                          // B*N = 262144
    dim3 grid(rows / BM);                                // 4096 blocks
    smod_kernel<<<grid, 256, 0, stream>>>(x, style, weight, bias, affw, affb, outp);
}